// Round 9
// baseline (183.435 us; speedup 1.0000x reference)
//
#include <hip/hip_runtime.h>
#include <hip/hip_bf16.h>
#include <cstdint>
#include <cstddef>

typedef unsigned short u16;
typedef __attribute__((ext_vector_type(8))) __bf16 bf16x8;
typedef __attribute__((ext_vector_type(16))) float f32x16;

#define LPOS 4096
#define CDIM 256

#if __has_builtin(__builtin_amdgcn_exp2f)
#define EXP2(x) __builtin_amdgcn_exp2f(x)
#else
#define EXP2(x) exp2f(x)
#endif

// async global->LDS 16B: LDS dst must be wave-uniform base + lane*16
#define GLOAD_LDS16(g, l)                                                      \
  __builtin_amdgcn_global_load_lds(                                            \
      (const __attribute__((address_space(1))) void*)(g),                      \
      (__attribute__((address_space(3))) void*)(l), 16, 0, 0)

__device__ __forceinline__ unsigned f2bfbits(float x) {
  union { float f; unsigned u; } v; v.f = x;
  return (v.u + 0x7FFFu + ((v.u >> 16) & 1u)) >> 16;
}
__device__ __forceinline__ unsigned packbf(float a, float b) {
  __hip_bfloat162 h2 = __float22bfloat162_rn(make_float2(a, b));
  return *(unsigned*)&h2;
}

// ------- fused normalize: stats + normalize + transpose + bf16 cast --------
// Q (arr==0) is pre-scaled by log2(e): downstream uses exp2(Q.K) == exp(q.k).
__global__ void norm_fused(const float* __restrict__ t_in,
                           const float* __restrict__ s_in,
                           const float* __restrict__ r_in,
                           u16* __restrict__ qn, u16* __restrict__ ksn,
                           u16* __restrict__ krn) {
  __shared__ float tile[256 * 33];
  __shared__ float sums[256], sqs[256];
  __shared__ float mv[32], ivv[32];
  int idx = blockIdx.x;
  int ab = idx >> 7, lt = idx & 127;
  int arr = ab >> 1, b = ab & 1;
  int l0 = lt * 32;
  const float* inp = (arr == 0 ? t_in : arr == 1 ? s_in : r_in) + (size_t)b * CDIM * LPOS;
  u16* outp = (arr == 0 ? qn : arr == 1 ? ksn : krn) + (size_t)b * LPOS * CDIM;
  float scale = (arr == 0) ? 1.4426950408889634f : 1.0f;
  int t = threadIdx.x;
  int cg = t >> 5, l = t & 31;
  float sum = 0.f, sq = 0.f;
#pragma unroll 8
  for (int cc = 0; cc < 32; ++cc) {
    int c = cg * 32 + cc;
    float v = inp[(size_t)c * LPOS + l0 + l];
    tile[c * 33 + l] = v;
    sum += v; sq += v * v;
  }
  sums[t] = sum; sqs[t] = sq;
  __syncthreads();
  if (t < 32) {
    float s = 0.f, q = 0.f;
#pragma unroll
    for (int g = 0; g < 8; ++g) { s += sums[g * 32 + t]; q += sqs[g * 32 + t]; }
    float mean = s * (1.0f / CDIM);
    float nsq = q - s * s * (1.0f / CDIM);
    mv[t] = mean;
    ivv[t] = rsqrtf(fmaxf(nsq, 1e-20f)) * scale;
  }
  __syncthreads();
  int c2 = t & 127, ph = t >> 7;
#pragma unroll 4
  for (int rr = 0; rr < 16; ++rr) {
    int pos = ph + rr * 2;
    float m = mv[pos], iv = ivv[pos];
    float v0 = (tile[(2 * c2) * 33 + pos] - m) * iv;
    float v1 = (tile[(2 * c2 + 1) * 33 + pos] - m) * iv;
    *(unsigned*)&outp[(size_t)(l0 + pos) * CDIM + 2 * c2] = packbf(v0, v1);
  }
}

// ------- build combined V tensors, OCTET-MAJOR: [b][j>>3][c][j&7] bf16 -------
// This makes the flash consumer loads (64 lanes = 64 consecutive c-rows of one
// j-octet, 16B each) a single fully-coalesced 1KB transaction per instruction.
// vs: c 0..3 src_feats, 4 ones, 5..31 zero       (CV=32)
// vr: c 0..150 sem, 151..154 ref_feats, 155 ones, 156..159 zero  (CV=160)
__global__ void build_v(const float* __restrict__ sf, const float* __restrict__ rf,
                        const float* __restrict__ sem,
                        u16* __restrict__ vs, u16* __restrict__ vr) {
  int t = blockIdx.x * 256 + threadIdx.x;
  const int NVS = 2 * 32 * 4096;
  if (t < NVS) {
    int b = t >> 17;
    int c = (t >> 12) & 31;
    int j = t & 4095;
    float v = (c < 4) ? sf[((size_t)b * 4 + c) * LPOS + j] : (c == 4 ? 1.0f : 0.0f);
    vs[(((size_t)b * 512 + (j >> 3)) * 32 + c) * 8 + (j & 7)] = (u16)f2bfbits(v);
  } else {
    int t2 = t - NVS;
    if (t2 < 2 * 160 * 4096) {
      int b = t2 / (160 * 4096);
      int rr = t2 % (160 * 4096);
      int c = rr >> 12, j = rr & 4095;
      float v = (c < 151) ? sem[((size_t)b * 151 + c) * LPOS + j]
              : (c < 155) ? rf[((size_t)b * 4 + (c - 151)) * LPOS + j]
              : (c == 155) ? 1.0f : 0.0f;
      vr[(((size_t)b * 512 + (j >> 3)) * 160 + c) * 8 + (j & 7)] = (u16)f2bfbits(v);
    }
  }
}

// ---------------- fused flash soft-warp ----------------
// S^T orientation: D[m=j][n=i] = sum_c K[j][c] * Q[i][c]
// PV: D[m=c][n=i]  = sum_j V[c][j] * P[j][i]
// R9: j-tile 64 (MT=2) -> half the barriers for the same work; V entirely out
// of LDS (octet-major coalesced register loads; groups 0-1 pre-stage, groups
// 2-3 post-QK so their vmcnt wait hits a ~500-cycle-old stage). K-only LDS
// 2x32KB. Grid sized for exactly 2 dispatch rounds.
template <int CT>
__device__ __forceinline__ void flash_body(
    const u16* __restrict__ qb, const u16* __restrict__ kb,
    const u16* __restrict__ vb, float* __restrict__ dst,
    u16 (*lds)[16384], int wave, int lane, int i_wave, int j_base, int iters) {
  int h = lane >> 5, ln = lane & 31;
  const int CV = CT * 32;       // V channel rows (160 ref / 32 src)

  // Q fragments: B[k=c][n=i], lane n=ln, k = kt*16 + h*8 + t
  bf16x8 qf[16];
  const u16* qrow = qb + (size_t)(i_wave + ln) * CDIM;
#pragma unroll
  for (int kt = 0; kt < 16; ++kt)
    qf[kt] = *(const bf16x8*)(qrow + kt * 16 + h * 8);

  f32x16 O[CT];
#pragma unroll
  for (int c = 0; c < CT; ++c)
#pragma unroll
    for (int t = 0; t < 16; ++t) O[c][t] = 0.0f;

  // K stage: 64 rows x 256c, XOR-swizzled 16B chunks; slot G = rows 2G,2G+1.
  auto stage = [&](int j0s, int buf) {
#pragma unroll
    for (int g = 0; g < 8; ++g) {
      int G = wave * 8 + g;
      int j = 2 * G + h;
      GLOAD_LDS16(kb + (size_t)(j0s + j) * CDIM + (ln ^ (j & 7)) * 8,
                  &lds[buf][G * 512]);
    }
  };

  // K ds_read swizzle (validated R4-R8): row r = mt*32+ln at u16 offset
  // mt*8192 + kread_base + 16*((kt&3)^q) + 64*(kt>>2)
  int kread_base = ln * 256 + 8 * (h ^ (ln & 1));
  int q = (ln >> 1) & 3;

  stage(j_base, 0);

  auto iter_body = [&](int jt, int buf) {
    int j0 = j_base + jt * 64;
    int o0 = j0 >> 3;                 // base j-octet of this tile
    int bo = buf * 16384;             // literal after unroll
    __syncthreads();                  // drains prefetch(jt) — in flight a full iter

    // V consumer loads, groups 0-1 (j 0..31) BEFORE the stage (FIFO-safe).
    // A-frag: lane ln = channel row ct*32+ln, octet 2*kt2+h. Coalesced 1KB.
    bf16x8 vfA[2][CT], vfB[2][CT];
#pragma unroll
    for (int k2 = 0; k2 < 2; ++k2)
#pragma unroll
      for (int ct = 0; ct < CT; ++ct)
        vfA[k2][ct] = *(const bf16x8*)(vb +
            ((size_t)(o0 + 2 * k2 + h) * CV + ct * 32 + ln) * 8);
    if constexpr (CT == 1) {          // src: all 4 groups fit pre-stage
#pragma unroll
      for (int k2 = 0; k2 < 2; ++k2)
        vfB[k2][0] = *(const bf16x8*)(vb +
            ((size_t)(o0 + 2 * k2 + 4 + h) * CV + ln) * 8);
    }
    if (jt + 1 < iters) stage(j0 + 64, buf ^ 1);   // producer LAST

    // QK: A = K (LDS, swizzled, immediate offsets), B = Q (regs); 2 tiles
    f32x16 S0, S1;
#pragma unroll
    for (int t = 0; t < 16; ++t) { S0[t] = 0.0f; S1[t] = 0.0f; }
#pragma unroll
    for (int kt = 0; kt < 16; ++kt) {
      int ko = kread_base + 16 * ((kt & 3) ^ q) + 64 * (kt >> 2) + bo;
      bf16x8 a0 = *(const bf16x8*)&lds[0][ko];
      S0 = __builtin_amdgcn_mfma_f32_32x32x16_bf16(a0, qf[kt], S0, 0, 0, 0);
      bf16x8 a1 = *(const bf16x8*)&lds[0][ko + 8192];
      S1 = __builtin_amdgcn_mfma_f32_32x32x16_bf16(a1, qf[kt], S1, 0, 0, 0);
    }
    // ref: V groups 2-3 now — stage is ~QK-deep in flight, wait is cheap
    if constexpr (CT == 5) {
#pragma unroll
      for (int k2 = 0; k2 < 2; ++k2)
#pragma unroll
        for (int ct = 0; ct < CT; ++ct)
          vfB[k2][ct] = *(const bf16x8*)(vb +
              ((size_t)(o0 + 2 * k2 + 4 + h) * CV + ct * 32 + ln) * 8);
    }

    // Q pre-scaled by log2e: exp2(s) == exp(q.k)
#pragma unroll
    for (int t = 0; t < 16; ++t) { S0[t] = EXP2(S0[t]); S1[t] = EXP2(S1[t]); }

    // P^T C-layout -> PV B-frags. STATIC packs, u32 cndmask selects, xor-32.
    bf16x8 pb[4];
#pragma unroll
    for (int kt2 = 0; kt2 < 4; ++kt2) {
      const f32x16& S = (kt2 < 2) ? S0 : S1;
      int kh = kt2 & 1;
      unsigned c0 = packbf(S[kh * 8 + 0], S[kh * 8 + 1]);
      unsigned c1 = packbf(S[kh * 8 + 2], S[kh * 8 + 3]);
      unsigned c2 = packbf(S[kh * 8 + 4], S[kh * 8 + 5]);
      unsigned c3 = packbf(S[kh * 8 + 6], S[kh * 8 + 7]);
      unsigned keep0 = h ? c2 : c0, keep1 = h ? c3 : c1;
      unsigned send0 = h ? c0 : c2, send1 = h ? c1 : c3;
      unsigned recv0 = (unsigned)__shfl_xor((int)send0, 32, 64);
      unsigned recv1 = (unsigned)__shfl_xor((int)send1, 32, 64);
      union { unsigned u[4]; bf16x8 v; } tmp;
      tmp.u[0] = h ? recv0 : keep0;
      tmp.u[1] = h ? recv1 : keep1;
      tmp.u[2] = h ? keep0 : recv0;
      tmp.u[3] = h ? keep1 : recv1;
      pb[kt2] = tmp.v;
    }

    // PV: A = V (regs, coalesced-loaded), B = P
#pragma unroll
    for (int ct = 0; ct < CT; ++ct) {
      O[ct] = __builtin_amdgcn_mfma_f32_32x32x16_bf16(vfA[0][ct], pb[0], O[ct], 0, 0, 0);
      O[ct] = __builtin_amdgcn_mfma_f32_32x32x16_bf16(vfA[1][ct], pb[1], O[ct], 0, 0, 0);
      O[ct] = __builtin_amdgcn_mfma_f32_32x32x16_bf16(vfB[0][ct], pb[2], O[ct], 0, 0, 0);
      O[ct] = __builtin_amdgcn_mfma_f32_32x32x16_bf16(vfB[1][ct], pb[3], O[ct], 0, 0, 0);
    }
  };

  for (int jt = 0; jt < iters; jt += 2) {   // iters even
    iter_body(jt, 0);
    iter_body(jt + 1, 1);
  }

  // epilogue: D rows = c, cols = i
#pragma unroll
  for (int ct = 0; ct < CT; ++ct)
#pragma unroll
    for (int t = 0; t < 16; ++t) {
      int c = ct * 32 + (t & 3) + 8 * (t >> 2) + 4 * h;
      dst[(size_t)c * LPOS + i_wave + ln] = O[ct][t];
    }
}

// 64 KB LDS (2 x 32KB K-bufs), (256,2): full 256-reg budget (R2/R6: any
// tighter cap spills at 2x cost). Grid 128*nch = 1024 -> exactly 2 rounds.
__global__ __launch_bounds__(256, 2) void flash(
    const u16* __restrict__ qn, const u16* __restrict__ ksn, const u16* __restrict__ krn,
    const u16* __restrict__ vs, const u16* __restrict__ vr,
    float* __restrict__ nsrc, float* __restrict__ nref, int nch) {
  __shared__ u16 lds[2][16384];   // 64 KB
  int tid = threadIdx.x;
  int wave = tid >> 6, lane = tid & 63;
  int idx = blockIdx.x;
  bool is_ref = !(idx & 1);       // even=ref, odd=src: each CU gets a mix
  int r = idx >> 1;
  int chunk = r >> 6, b = (r >> 5) & 1, wgi = r & 31;
  int jchunk = LPOS / nch;
  int j_base = chunk * jchunk;
  int iters = jchunk / 64;
  int i_wave = wgi * 128 + wave * 32;
  const u16* qb = qn + (size_t)b * LPOS * CDIM;
  if (is_ref) {
    flash_body<5>(qb, krn + (size_t)b * LPOS * CDIM, vr + (size_t)b * 160 * LPOS,
                  nref + (size_t)(chunk * 2 + b) * 160 * LPOS,
                  lds, wave, lane, i_wave, j_base, iters);
  } else {
    flash_body<1>(qb, ksn + (size_t)b * LPOS * CDIM, vs + (size_t)b * 32 * LPOS,
                  nsrc + (size_t)(chunk * 2 + b) * 32 * LPOS,
                  lds, wave, lane, i_wave, j_base, iters);
  }
}

// ---------------- finalize: sum chunks, divide by ones-channel --------------
__global__ void finalize(const float* __restrict__ nsrc, const float* __restrict__ nref,
                         float* __restrict__ out, int nch) {
  int t = blockIdx.x * 256 + threadIdx.x;
  if (t >= 1302528) return;
  if (t < 32768) {                        // warped_src_feat [2][4][4096]
    int b = t >> 14, c = (t >> 12) & 3, i = t & 4095;
    float num = 0.f, den = 0.f;
    for (int k = 0; k < nch; ++k) {
      const float* base = nsrc + ((size_t)(k * 2 + b) * 32) * LPOS;
      num += base[(size_t)c * LPOS + i];
      den += base[(size_t)4 * LPOS + i];
    }
    out[t] = num / den;
  } else if (t < 65536) {                 // warped_ref_feat [2][4][4096]
    int t1 = t - 32768;
    int b = t1 >> 14, c = (t1 >> 12) & 3, i = t1 & 4095;
    float num = 0.f, den = 0.f;
    for (int k = 0; k < nch; ++k) {
      const float* base = nref + ((size_t)(k * 2 + b) * 160) * LPOS;
      num += base[(size_t)(151 + c) * LPOS + i];
      den += base[(size_t)155 * LPOS + i];
    }
    out[t] = num / den;
  } else {                                // warped_ref_seg [2][151][4096]
    int t2 = t - 65536;
    int b = t2 / 618496;
    int rr = t2 % 618496;
    int c = rr >> 12, i = rr & 4095;
    float num = 0.f, den = 0.f;
    for (int k = 0; k < nch; ++k) {
      const float* base = nref + ((size_t)(k * 2 + b) * 160) * LPOS;
      num += base[(size_t)c * LPOS + i];
      den += base[(size_t)155 * LPOS + i];
    }
    out[t] = num / den;
  }
}

extern "C" void kernel_launch(void* const* d_in, const int* in_sizes, int n_in,
                              void* d_out, int out_size, void* d_ws, size_t ws_size,
                              hipStream_t stream) {
  const float* trg  = (const float*)d_in[0];
  const float* srcp = (const float*)d_in[1];
  const float* refp = (const float*)d_in[2];
  const float* sfeat = (const float*)d_in[3];
  const float* rfeat = (const float*)d_in[4];
  const float* rsem  = (const float*)d_in[5];
  float* out = (float*)d_out;

  char* ws = (char*)d_ws;
  size_t o = 0;
  auto alloc = [&](size_t bytes) -> char* {
    char* p = ws + o;
    o += (bytes + 255) & ~(size_t)255;
    return p;
  };
  u16* qn  = (u16*)alloc(2ull * LPOS * CDIM * 2);
  u16* ksn = (u16*)alloc(2ull * LPOS * CDIM * 2);
  u16* krn = (u16*)alloc(2ull * LPOS * CDIM * 2);
  u16* vs  = (u16*)alloc(2ull * 32 * LPOS * 2);
  u16* vr  = (u16*)alloc(2ull * 160 * LPOS * 2);

  size_t fixed = o;
  int nch = 8;
  for (;;) {
    size_t need = fixed + 512 +
                  (size_t)nch * 2 * 32 * LPOS * 4 +
                  (size_t)nch * 2 * 160 * LPOS * 4;
    if (need <= ws_size || nch == 2) break;
    nch >>= 1;
  }
  float* nsrc = (float*)alloc((size_t)nch * 2 * 32 * LPOS * 4);
  float* nref = (float*)alloc((size_t)nch * 2 * 160 * LPOS * 4);

  hipLaunchKernelGGL(norm_fused, dim3(768), dim3(256), 0, stream,
                     trg, srcp, refp, qn, ksn, krn);
  hipLaunchKernelGGL(build_v, dim3(6144), dim3(256), 0, stream,
                     sfeat, rfeat, rsem, vs, vr);
  hipLaunchKernelGGL(flash, dim3(128 * nch), dim3(256), 0, stream,
                     qn, ksn, krn, vs, vr, nsrc, nref, nch);
  hipLaunchKernelGGL(finalize, dim3(5088), dim3(256), 0, stream,
                     nsrc, nref, out, nch);
}